// Round 5
// baseline (1997.824 us; speedup 1.0000x reference)
//
#include <hip/hip_runtime.h>
#include <hip/hip_bf16.h>
#include <math.h>

typedef __hip_bfloat16 bf16;
typedef __attribute__((ext_vector_type(8))) short short8;
typedef __attribute__((ext_vector_type(4))) float f32x4;

#define BB  4
#define NN  4096
#define SS  1024
#define KNS 32
#define C1  70

__device__ __forceinline__ float b2f(bf16 x){ return __bfloat162float(x); }

__device__ __forceinline__ float ld(const void* p, size_t i, bool F){
    return F ? ((const float*)p)[i] : __bfloat162float(((const bf16*)p)[i]);
}
__device__ __forceinline__ void st(void* p, size_t i, float v, bool F){
    if (F) ((float*)p)[i] = v; else ((bf16*)p)[i] = __float2bfloat16(v);
}
__device__ __forceinline__ unsigned short f2us(float x){
    __hip_bfloat16 h = __float2bfloat16(x);
    return *reinterpret_cast<unsigned short*>(&h);
}
__device__ __forceinline__ float us2f(unsigned short u){
    return __uint_as_float(((unsigned)u) << 16);
}

// ---------------- init: dtype detect + zero stats ----------------
__global__ void init_kernel(const void* xyz, double* __restrict__ M,
                            double* __restrict__ sums, int* __restrict__ flag){
    __shared__ int cnt;
    const int t = threadIdx.x;
    if (t == 0) cnt = 0;
    if (t < 105) M[t] = 0.0;
    if (t < 256) sums[t] = 0.0;
    __syncthreads();
    int c = 0;
    for (int i = t; i < 2048; i += 256){
        float v = __bfloat162float(((const bf16*)xyz)[i]);
        if (!(fabsf(v) <= 1.5f)) c++;   // catches NaN too
    }
    atomicAdd(&cnt, c);
    __syncthreads();
    if (t == 0) *flag = (cnt > 10) ? 1 : 0;
}

// ---------------- FPS: 512 thr x 8 pts, u64 packed reduce ----------------
__global__ __launch_bounds__(512) void fps_kernel(const void* __restrict__ xyz,
        float* __restrict__ nxf, void* __restrict__ out, const int* __restrict__ flag){
    __shared__ float4 pts[NN];     // 64 KB
    __shared__ int sidx[SS];
    __shared__ unsigned long long skey[2][8];
    const bool F = (*flag != 0);
    const int b = blockIdx.x, t = threadIdx.x, lane = t & 63, w = t >> 6;
    float px[8], py[8], pz[8], mind[8];
#pragma unroll
    for (int j = 0; j < 8; j++){
        int i = j*512 + t;
        float X = ld(xyz, (size_t)(b*NN+i)*3+0, F);
        float Y = ld(xyz, (size_t)(b*NN+i)*3+1, F);
        float Z = ld(xyz, (size_t)(b*NN+i)*3+2, F);
        px[j] = X; py[j] = Y; pz[j] = Z; mind[j] = 1e10f;
        pts[i] = make_float4(X, Y, Z, 0.f);
    }
    if (t == 0) sidx[0] = 0;
    __syncthreads();
    float4 q = pts[0];
    for (int s = 1; s < SS; s++){
        float bd = -1.f; int bi = 0;
#pragma unroll
        for (int j = 0; j < 8; j++){
            float dx = __fsub_rn(px[j], q.x);
            float dy = __fsub_rn(py[j], q.y);
            float dz = __fsub_rn(pz[j], q.z);
            float d  = __fadd_rn(__fadd_rn(__fmul_rn(dx,dx), __fmul_rn(dy,dy)), __fmul_rn(dz,dz));
            float m = fminf(mind[j], d); mind[j] = m;
            if (m > bd){ bd = m; bi = j*512 + t; }   // ascending index -> strict > keeps first
        }
        // pack: max d, tie -> min index (d>=0 so float bits order as uint)
        unsigned long long key = ((unsigned long long)__float_as_uint(bd) << 32)
                               | (unsigned)(~bi);
#pragma unroll
        for (int off = 1; off < 64; off <<= 1){
            unsigned long long o = __shfl_xor(key, off);
            if (o > key) key = o;
        }
        const int par = s & 1;
        if (lane == 0) skey[par][w] = key;
        __syncthreads();
        unsigned long long k0 = skey[par][0], k1 = skey[par][1];
        unsigned long long k2 = skey[par][2], k3 = skey[par][3];
        unsigned long long k4 = skey[par][4], k5 = skey[par][5];
        unsigned long long k6 = skey[par][6], k7 = skey[par][7];
        if (k1 > k0) k0 = k1;
        if (k3 > k2) k2 = k3;
        if (k5 > k4) k4 = k5;
        if (k7 > k6) k6 = k7;
        if (k2 > k0) k0 = k2;
        if (k6 > k4) k4 = k6;
        if (k4 > k0) k0 = k4;
        int ix = (int)(~(unsigned)(k0 & 0xffffffffull));
        if (t == 0) sidx[s] = ix;
        q = pts[ix];
    }
    __syncthreads();
    const size_t o1 = (size_t)BB*SS*128;
    for (int s2 = t; s2 < SS; s2 += 512){
        int i = sidx[s2];
        float4 p = pts[i];
        nxf[(b*SS+s2)*3+0] = p.x; nxf[(b*SS+s2)*3+1] = p.y; nxf[(b*SS+s2)*3+2] = p.z;
        st(out, o1 + (size_t)(b*SS+s2)*3+0, p.x, F);
        st(out, o1 + (size_t)(b*SS+s2)*3+1, p.y, F);
        st(out, o1 + (size_t)(b*SS+s2)*3+2, p.z, F);
    }
}

// ---------------- ball query ----------------
__global__ __launch_bounds__(256) void ball_kernel(const void* __restrict__ xyz,
        const float* __restrict__ nxf, int* __restrict__ idx, const int* __restrict__ flag){
    __shared__ float sx[NN], sy[NN], sz[NN];
    const bool F = (*flag != 0);
    const int b = blockIdx.x, t = threadIdx.x;
    for (int i = t; i < NN; i += 256){
        sx[i] = ld(xyz, (size_t)(b*NN+i)*3+0, F);
        sy[i] = ld(xyz, (size_t)(b*NN+i)*3+1, F);
        sz[i] = ld(xyz, (size_t)(b*NN+i)*3+2, F);
    }
    __syncthreads();
    const int s = blockIdx.y*256 + t;
    const float px = nxf[(b*SS+s)*3+0];
    const float py = nxf[(b*SS+s)*3+1];
    const float pz = nxf[(b*SS+s)*3+2];
    const float R2 = 0.2f*0.2f;
    int* op = idx + (size_t)(b*SS+s)*KNS;
    int cnt = 0;
    for (int i = 0; i < NN; i++){
        float dx = __fsub_rn(px, sx[i]);
        float dy = __fsub_rn(py, sy[i]);
        float dz = __fsub_rn(pz, sz[i]);
        float d2 = __fadd_rn(__fadd_rn(__fmul_rn(dx,dx), __fmul_rn(dy,dy)), __fmul_rn(dz,dz));
        if (d2 < R2){
            op[cnt++] = i;
            if (cnt == KNS) break;
        }
    }
    for (; cnt < KNS; cnt++) op[cnt] = -1;
}

// ---------------- BN1 stats v3: register outer-products, no LDS inner loop ----------------
__global__ __launch_bounds__(256) void bn1_stats(const void* __restrict__ xyz,
        const int* __restrict__ idx, const void* __restrict__ fpt, double* __restrict__ M,
        const int* __restrict__ flag){
    __shared__ float sfp[24];
    const bool F = (*flag != 0);
    const int t = threadIdx.x, lane = t & 63;
    if (t < 24) sfp[t] = ld(fpt, t, F);
    __syncthreads();
    float acc[105];
#pragma unroll
    for (int q = 0; q < 105; q++) acc[q] = 0.f;
    for (int it = 0; it < 8; it++){
        const int row = blockIdx.x*2048 + it*256 + t;
        const int b = row >> 15;
        const int id = idx[row];
        float gx = 0.f, gy = 0.f, gz = 0.f;
        if (id >= 0){
            gx = ld(xyz, (size_t)(b*NN+id)*3+0, F);
            gy = ld(xyz, (size_t)(b*NN+id)*3+1, F);
            gz = ld(xyz, (size_t)(b*NN+id)*3+2, F);
        }
#pragma unroll
        for (int v = 0; v < 8; v++){
            float fxv = sfp[v*3+0], fyv = sfp[v*3+1], fzv = sfp[v*3+2];
            float ax = gx - fxv, ay = gy - fyv, az = gz - fzv;
            float eu = sqrtf(ax*ax + ay*ay + az*az);
            float fv[14];
            fv[0] = -ax; fv[1] = -ay; fv[2] = -az;
            fv[3] =  ax; fv[4] =  ay; fv[5] =  az;
            fv[6] = eu;  fv[7] = gx;  fv[8] = gy; fv[9] = gz;
            fv[10] = fxv; fv[11] = fyv; fv[12] = fzv; fv[13] = 1.0f;
            int q = 0;
#pragma unroll
            for (int i = 0; i < 14; i++)
#pragma unroll
                for (int j = i; j < 14; j++){
                    acc[q] = fmaf(fv[i], fv[j], acc[q]);
                    q++;
                }
        }
    }
#pragma unroll
    for (int q = 0; q < 105; q++){
        float s = acc[q];
#pragma unroll
        for (int off = 1; off < 64; off <<= 1) s += __shfl_xor(s, off);
        if (lane == 0) atomicAdd(&M[q], (double)s);
    }
}

// ---------------- BN1 finalize ----------------
__global__ __launch_bounds__(128) void bn1_final(const double* __restrict__ M,
        const void* __restrict__ w10, const void* __restrict__ b10,
        const void* __restrict__ g1, const void* __restrict__ bt1, float* __restrict__ bn1,
        const int* __restrict__ flag){
    __shared__ double Mm[14][14];
    __shared__ double mv[14];
    const bool F = (*flag != 0);
    const int t = threadIdx.x;
    if (t < 105){
        int e = t, i = 0, off = 0;
        while (e - off >= 14 - i){ off += 14 - i; i++; }
        int j = i + (e - off);
        double val = M[t];
        Mm[i][j] = val; Mm[j][i] = val;
    }
    __syncthreads();
    const double K = 1048576.0;
    if (t < 14) mv[t] = Mm[t][13] / K;
    __syncthreads();
    if (t < 64){
        double wc[13];
        for (int i = 0; i < 13; i++) wc[i] = (double)ld(w10, i*64+t, F);
        double mean = (double)ld(b10, t, F);
        for (int i = 0; i < 13; i++) mean += mv[i]*wc[i];
        double var = 0.0;
        for (int i = 0; i < 13; i++)
            for (int j = 0; j < 13; j++)
                var += wc[i]*wc[j]*(Mm[i][j]/K - mv[i]*mv[j]);
        float sc = ld(g1, t, F) / sqrtf((float)var + 1e-5f);
        bn1[t] = sc;
        bn1[64+t] = ld(bt1, t, F) - (float)mean * sc;
    }
}

// ---------------- m1: MFMA phase B (3-pass bf16 hi/lo), per-wave pipeline ----------------
__global__ __launch_bounds__(256) void m1_kernel(
        const void* __restrict__ xyz, const void* __restrict__ f, const void* __restrict__ fpt,
        const void* __restrict__ w10, const void* __restrict__ b10,
        const void* __restrict__ w11, const void* __restrict__ b11,
        const float* __restrict__ nxf, const int* __restrict__ idx,
        const float* __restrict__ bn1, float* __restrict__ agg, const int* __restrict__ flag){
    __shared__ short sthi[4*2*8*72];
    __shared__ short stlo[4*2*8*72];
    __shared__ float gfb[4*2*80];
    const bool F = (*flag != 0);
    const int t = threadIdx.x, lane = t & 63, w = t >> 6;
    const int kq = lane >> 4, cn = lane & 15;

    short8 Bh[2][5], Bl[2][5];
#pragma unroll
    for (int ks = 0; ks < 2; ks++)
#pragma unroll
    for (int nt = 0; nt < 5; nt++){
        short8 bh, bl;
#pragma unroll
        for (int j = 0; j < 8; j++){
            int k = ks*32 + kq*8 + j;
            int c = nt*16 + cn;
            float wv = (c < C1) ? ld(w11, (size_t)k*C1 + c, F) : 0.f;
            unsigned short h = f2us(wv);
            unsigned short l2 = f2us(wv - us2f(h));
            bh[j] = (short)h; bl[j] = (short)l2;
        }
        Bh[ks][nt] = bh; Bl[ks][nt] = bl;
    }
    float binit[5];
#pragma unroll
    for (int nt = 0; nt < 5; nt++){
        int c = nt*16 + cn;
        binit[nt] = (c < C1) ? ld(b11, c, F) : 0.f;
    }
    float W10c[13];
#pragma unroll
    for (int i = 0; i < 13; i++) W10c[i] = ld(w10, i*64+lane, F);
    const float b10v = ld(b10, lane, F);
    const float sc1 = bn1[lane], sh1 = bn1[64+lane];
    float fx[8], fy[8], fz[8];
#pragma unroll
    for (int v = 0; v < 8; v++){
        fx[v] = ld(fpt, v*3+0, F); fy[v] = ld(fpt, v*3+1, F); fz[v] = ld(fpt, v*3+2, F);
    }
    const int quad = lane >> 4;
    const int rr = quad >> 1;
    const int hh = quad & 1;
    const int mA = lane & 15;
    const int rA = mA >> 3, vA = mA & 7;

    const int wid = blockIdx.x*4 + w;
    for (int p = 0; p < 16; p++){
        const int rowbase = wid*32 + p*2;
        int ids[2];
#pragma unroll
        for (int r = 0; r < 2; r++){
            const int row = rowbase + r;
            const int b = row >> 15, s = (row >> 5) & 1023;
            const int id = idx[row];
            ids[r] = id;
            float gx = 0.f, gy = 0.f, gz = 0.f, fv0 = 0.f, fv1 = 0.f;
            if (id >= 0){
                gx = ld(xyz, (size_t)(b*NN+id)*3+0, F);
                gy = ld(xyz, (size_t)(b*NN+id)*3+1, F);
                gz = ld(xyz, (size_t)(b*NN+id)*3+2, F);
                if (lane >= 6) fv0 = ld(f, (size_t)(b*NN+id)*64 + (lane-6), F);
                if (lane < 6)  fv1 = ld(f, (size_t)(b*NN+id)*64 + (58+lane), F);
            }
            const float nxx = nxf[(b*SS+s)*3+0], nxy = nxf[(b*SS+s)*3+1], nxz = nxf[(b*SS+s)*3+2];
            float gf0;
            if (lane == 0) gf0 = gx; else if (lane == 1) gf0 = gy; else if (lane == 2) gf0 = gz;
            else if (lane == 3) gf0 = gx - nxx; else if (lane == 4) gf0 = gy - nxy;
            else if (lane == 5) gf0 = gz - nxz; else gf0 = fv0;
            gfb[w*160 + r*80 + lane] = gf0;
            if (lane < 6)       gfb[w*160 + r*80 + 64 + lane] = fv1;
            else if (lane < 16) gfb[w*160 + r*80 + 64 + lane] = 0.f;
            const int sb = ((w*2 + r)*8)*72 + lane;
#pragma unroll
            for (int v = 0; v < 8; v++){
                float ax = gx - fx[v], ay = gy - fy[v], az = gz - fz[v];
                float eu = sqrtf(ax*ax + ay*ay + az*az);
                float z = b10v;
                z = fmaf(-ax, W10c[0], z); z = fmaf(-ay, W10c[1], z); z = fmaf(-az, W10c[2], z);
                z = fmaf( ax, W10c[3], z); z = fmaf( ay, W10c[4], z); z = fmaf( az, W10c[5], z);
                z = fmaf( eu, W10c[6], z);
                z = fmaf( gx, W10c[7], z); z = fmaf( gy, W10c[8], z); z = fmaf( gz, W10c[9], z);
                z = fmaf(fx[v], W10c[10], z); z = fmaf(fy[v], W10c[11], z); z = fmaf(fz[v], W10c[12], z);
                float a1 = fmaxf(fmaf(z, sc1, sh1), 0.f);
                unsigned short h = f2us(a1);
                unsigned short l2 = f2us(a1 - us2f(h));
                sthi[sb + v*72] = (short)h;
                stlo[sb + v*72] = (short)l2;
            }
        }
        f32x4 acc[5];
#pragma unroll
        for (int nt = 0; nt < 5; nt++){
            f32x4 a; a[0] = binit[nt]; a[1] = binit[nt]; a[2] = binit[nt]; a[3] = binit[nt];
            acc[nt] = a;
        }
        const int aoff = ((w*2 + rA)*8 + vA)*72 + kq*8;
#pragma unroll
        for (int ks = 0; ks < 2; ks++){
            short8 ahi = *(const short8*)&sthi[aoff + ks*32];
            short8 alo = *(const short8*)&stlo[aoff + ks*32];
#pragma unroll
            for (int nt = 0; nt < 5; nt++){
                acc[nt] = __builtin_amdgcn_mfma_f32_16x16x32_bf16(ahi, Bh[ks][nt], acc[nt], 0, 0, 0);
                acc[nt] = __builtin_amdgcn_mfma_f32_16x16x32_bf16(alo, Bh[ks][nt], acc[nt], 0, 0, 0);
                acc[nt] = __builtin_amdgcn_mfma_f32_16x16x32_bf16(ahi, Bl[ks][nt], acc[nt], 0, 0, 0);
            }
        }
        const bool msk = ((rr == 0 ? ids[0] : ids[1]) < 0);
#pragma unroll
        for (int nt = 0; nt < 5; nt++){
            const int col = nt*16 + cn;
            float gfv = gfb[w*160 + rr*80 + col];
            f32x4 a = acc[nt];
            float p0 = a[0]*gfv, p1 = a[1]*gfv, p2 = a[2]*gfv, p3 = a[3]*gfv;
            float mx = fmaxf(fmaxf(p0, p1), fmaxf(p2, p3));
            mx = fmaxf(mx, __shfl_xor(mx, 16));
            float e0 = __expf(p0 - mx), e1 = __expf(p1 - mx);
            float e2 = __expf(p2 - mx), e3 = __expf(p3 - mx);
            float den4 = (e0 + e1) + (e2 + e3);
            float num4 = fmaf(e3, p3, fmaf(e2, p2, fmaf(e1, p1, e0*p0)));
            float den = den4 + __shfl_xor(den4, 16);
            float num = num4 + __shfl_xor(num4, 16);
            float outv = num / den;
            if (hh == 0 && col < C1){
                agg[(size_t)(rowbase + rr)*C1 + col] = msk ? 0.f : outv;
            }
        }
    }
}

// ---------------- prep1: raw f32 weights (no bn2 dependency) ----------------
__global__ __launch_bounds__(256) void prep1_kernel(
        const void* __restrict__ w20, const void* __restrict__ w21,
        const void* __restrict__ rw, const void* __restrict__ b20,
        const void* __restrict__ b21, const void* __restrict__ rb,
        float* __restrict__ w20r, float* __restrict__ w21f, float* __restrict__ rwf,
        float* __restrict__ b20r, float* __restrict__ bof, const int* __restrict__ flag){
    const bool F = (*flag != 0);
    int e = blockIdx.x*256 + threadIdx.x;
    if (e < 8960){ w20r[e] = ld(w20, e, F); return; }
    int e2 = e - 8960;
    if (e2 < 16384){ w21f[e2] = ld(w21, e2, F); return; }
    int e3 = e2 - 16384;
    if (e3 < 8192){ rwf[e3] = ld(rw, e3, F); return; }
    int e4 = e3 - 8192;
    if (e4 < 128){
        b20r[e4] = ld(b20, e4, F);
        bof[e4]  = ld(b21, e4, F) + ld(rb, e4, F);
    }
}

// ---------------- BN2 stats v3: tiled GEMM, agg read once ----------------
__global__ __launch_bounds__(256) void bn2_stats(const float* __restrict__ agg,
        const float* __restrict__ w20r, const float* __restrict__ b20r,
        double* __restrict__ sums){
    __shared__ float aggT[70*65];   // [k][r]
    const int t = threadIdx.x, lane = t & 63;
    const int wbase = __builtin_amdgcn_readfirstlane((t >> 6) << 5);
    float binit[32];
#pragma unroll
    for (int j = 0; j < 32; j++) binit[j] = b20r[wbase + j];
    float accs[32], accq[32];
#pragma unroll
    for (int j = 0; j < 32; j++){ accs[j] = 0.f; accq[j] = 0.f; }
    for (int it = 0; it < 8; it++){
        const int rowbase = blockIdx.x*512 + it*64;
        __syncthreads();
        for (int e = t; e < 70*64; e += 256){
            int r = e / 70, k = e - r*70;
            aggT[k*65 + r] = agg[(size_t)rowbase*70 + e];
        }
        __syncthreads();
        float z[32];
#pragma unroll
        for (int j = 0; j < 32; j++) z[j] = binit[j];
#pragma unroll 2
        for (int k = 0; k < 70; k++){
            float av = aggT[k*65 + lane];
            const float* wr = w20r + k*128 + wbase;
#pragma unroll
            for (int j = 0; j < 32; j++) z[j] = fmaf(av, wr[j], z[j]);
        }
#pragma unroll
        for (int j = 0; j < 32; j++){
            accs[j] += z[j];
            accq[j] = fmaf(z[j], z[j], accq[j]);
        }
    }
#pragma unroll
    for (int j = 0; j < 32; j++){
        float s = accs[j], q = accq[j];
#pragma unroll
        for (int off = 1; off < 64; off <<= 1){
            s += __shfl_xor(s, off);
            q += __shfl_xor(q, off);
        }
        if (lane == 0){
            atomicAdd(&sums[wbase + j], (double)s);
            atomicAdd(&sums[128 + wbase + j], (double)q);
        }
    }
}

// ---------------- BN2 finalize ----------------
__global__ void bn2_final(const double* __restrict__ sums, const void* __restrict__ g2,
        const void* __restrict__ bt2, float* __restrict__ bn2, const int* __restrict__ flag){
    const bool F = (*flag != 0);
    int t = threadIdx.x; // 128
    const double K = 131072.0;
    double mean = sums[t] / K;
    double var = sums[128+t] / K - mean*mean;
    float sc = ld(g2, t, F) / sqrtf((float)var + 1e-5f);
    bn2[t] = sc;
    bn2[128+t] = ld(bt2, t, F) - (float)mean * sc;
}

// ---------------- prep2: fold bn2 into w20 ----------------
__global__ __launch_bounds__(256) void prep2_kernel(
        const float* __restrict__ w20r, const float* __restrict__ b20r,
        const float* __restrict__ bn2,
        float* __restrict__ w20f, float* __restrict__ b20f){
    int e = blockIdx.x*256 + threadIdx.x;
    if (e < 8960){ w20f[e] = w20r[e] * bn2[e & 127]; return; }
    int e2 = e - 8960;
    if (e2 < 128){ b20f[e2] = b20r[e2]*bn2[e2] + bn2[128+e2]; }
}

// ---------------- final: lane=row, regs=32 channels/wave ----------------
__global__ __launch_bounds__(256) void final_kernel(
        const float* __restrict__ agg, const void* __restrict__ f, const int* __restrict__ idx,
        const float* __restrict__ w20f, const float* __restrict__ b20f,
        const float* __restrict__ w21f, const float* __restrict__ rwf,
        const float* __restrict__ bof,
        void* __restrict__ out, const int* __restrict__ flag){
    __shared__ float aggT[70*65];
    __shared__ float gfs[64*65];
    __shared__ float wmids[128*64];
    __shared__ float obuf[256];
    const bool F = (*flag != 0);
    const int t = threadIdx.x, lane = t & 63;
    const int wbase = __builtin_amdgcn_readfirstlane((t >> 6) << 5);
    const int rowbase = blockIdx.x * 64;
    for (int e = t; e < 70*64; e += 256){
        int r = e / 70, k = e - r*70;
        aggT[k*65 + r] = agg[(size_t)rowbase*70 + e];
    }
    for (int e = t; e < 64*64; e += 256){
        int r = e >> 6, cin = e & 63;
        int id = idx[rowbase + r];
        int b = (rowbase + r) >> 15;
        gfs[cin*65 + r] = (id >= 0) ? ld(f, (size_t)(b*NN+id)*64 + cin, F) : 0.f;
    }
    __syncthreads();
    float acc[32];
#pragma unroll
    for (int j = 0; j < 32; j++) acc[j] = b20f[wbase + j];
#pragma unroll 2
    for (int k = 0; k < 70; k++){
        float av = aggT[k*65 + lane];
        const float* wr = w20f + k*128 + wbase;
#pragma unroll
        for (int j = 0; j < 32; j++) acc[j] = fmaf(av, wr[j], acc[j]);
    }
#pragma unroll
    for (int j = 0; j < 32; j++)
        wmids[(wbase + j)*64 + lane] = fmaxf(acc[j], 0.f);
    __syncthreads();
    float acc2[32];
#pragma unroll
    for (int j = 0; j < 32; j++) acc2[j] = bof[wbase + j];
#pragma unroll 2
    for (int k = 0; k < 128; k++){
        float wv = wmids[k*64 + lane];
        const float* wr = w21f + k*128 + wbase;
#pragma unroll
        for (int j = 0; j < 32; j++) acc2[j] = fmaf(wv, wr[j], acc2[j]);
    }
#pragma unroll 2
    for (int k = 0; k < 64; k++){
        float gv = gfs[k*65 + lane];
        const float* wr = rwf + k*128 + wbase;
#pragma unroll
        for (int j = 0; j < 32; j++) acc2[j] = fmaf(gv, wr[j], acc2[j]);
    }
#pragma unroll
    for (int j = 0; j < 32; j++){
        float x = acc2[j];
        float y = 0.5f * x * (1.f + erff(x * 0.70710678118654752f));
#pragma unroll
        for (int off = 1; off < 32; off <<= 1)
            y = fmaxf(y, __shfl_xor(y, off));
        if ((lane & 31) == 0) obuf[(lane >> 5)*128 + wbase + j] = y;
    }
    __syncthreads();
    st(out, (size_t)blockIdx.x*256 + t, obuf[t], F);
}

extern "C" void kernel_launch(void* const* d_in, const int* in_sizes, int n_in,
                              void* d_out, int out_size, void* d_ws, size_t ws_size,
                              hipStream_t stream){
    const void* xyz = d_in[0];
    const void* f   = d_in[1];
    const void* fpt = d_in[2];
    const void* w10 = d_in[3];
    const void* b10 = d_in[4];
    const void* g1  = d_in[5];
    const void* bt1 = d_in[6];
    const void* w11 = d_in[7];
    const void* b11 = d_in[8];
    const void* w20 = d_in[9];
    const void* b20 = d_in[10];
    const void* g2  = d_in[11];
    const void* bt2 = d_in[12];
    const void* w21 = d_in[13];
    const void* b21 = d_in[14];
    const void* rw  = d_in[15];
    const void* rb  = d_in[16];

    char* ws = (char*)d_ws;
    float*  nxf  = (float*) (ws + 0);
    int*    idx  = (int*)   (ws + 65536);
    double* M    = (double*)(ws + 655360);
    float*  bn1  = (float*) (ws + 786432);
    double* sums = (double*)(ws + 917504);
    float*  bn2  = (float*) (ws + 1048576);
    int*    flag = (int*)   (ws + 1050624);
    float*  w20f = (float*) (ws + 1114112);
    float*  w21f = (float*) (ws + 1179648);
    float*  rwf  = (float*) (ws + 1245184);
    float*  b20f = (float*) (ws + 1277952);
    float*  bof  = (float*) (ws + 1278464);
    float*  w20r = (float*) (ws + 1310720);
    float*  b20r = (float*) (ws + 1441792);
    float*  agg  = (float*) (ws + 2097152);

    init_kernel<<<1, 256, 0, stream>>>(xyz, M, sums, flag);
    fps_kernel<<<4, 512, 0, stream>>>(xyz, nxf, d_out, flag);
    ball_kernel<<<dim3(4,4), 256, 0, stream>>>(xyz, nxf, idx, flag);
    prep1_kernel<<<132, 256, 0, stream>>>(w20, w21, rw, b20, b21, rb,
                                          w20r, w21f, rwf, b20r, bof, flag);
    bn1_stats<<<64, 256, 0, stream>>>(xyz, idx, fpt, M, flag);
    bn1_final<<<1, 128, 0, stream>>>(M, w10, b10, g1, bt1, bn1, flag);
    m1_kernel<<<1024, 256, 0, stream>>>(xyz, f, fpt, w10, b10, w11, b11, nxf, idx, bn1, agg, flag);
    bn2_stats<<<256, 256, 0, stream>>>(agg, w20r, b20r, sums);
    bn2_final<<<1, 128, 0, stream>>>(sums, g2, bt2, bn2, flag);
    prep2_kernel<<<36, 256, 0, stream>>>(w20r, b20r, bn2, w20f, b20f);
    final_kernel<<<2048, 256, 0, stream>>>(agg, f, idx, w20f, b20f, w21f, rwf, bof, d_out, flag);
}

// Round 6
// 1466.536 us; speedup vs baseline: 1.3623x; 1.3623x over previous
//
#include <hip/hip_runtime.h>
#include <hip/hip_bf16.h>
#include <math.h>

typedef __hip_bfloat16 bf16;
typedef __attribute__((ext_vector_type(8))) short short8;
typedef __attribute__((ext_vector_type(4))) float f32x4;

#define BB  4
#define NN  4096
#define SS  1024
#define KNS 32
#define C1  70

__device__ __forceinline__ float b2f(bf16 x){ return __bfloat162float(x); }

__device__ __forceinline__ float ld(const void* p, size_t i, bool F){
    return F ? ((const float*)p)[i] : __bfloat162float(((const bf16*)p)[i]);
}
__device__ __forceinline__ void st(void* p, size_t i, float v, bool F){
    if (F) ((float*)p)[i] = v; else ((bf16*)p)[i] = __float2bfloat16(v);
}
__device__ __forceinline__ unsigned short f2us(float x){
    __hip_bfloat16 h = __float2bfloat16(x);
    return *reinterpret_cast<unsigned short*>(&h);
}
__device__ __forceinline__ float us2f(unsigned short u){
    return __uint_as_float(((unsigned)u) << 16);
}

// ---------------- init: dtype detect + zero stats ----------------
__global__ void init_kernel(const void* xyz, double* __restrict__ M,
                            double* __restrict__ sums, int* __restrict__ flag){
    __shared__ int cnt;
    const int t = threadIdx.x;
    if (t == 0) cnt = 0;
    if (t < 105) M[t] = 0.0;
    if (t < 256) sums[t] = 0.0;
    __syncthreads();
    int c = 0;
    for (int i = t; i < 2048; i += 256){
        float v = __bfloat162float(((const bf16*)xyz)[i]);
        if (!(fabsf(v) <= 1.5f)) c++;   // catches NaN too
    }
    atomicAdd(&cnt, c);
    __syncthreads();
    if (t == 0) *flag = (cnt > 10) ? 1 : 0;
}

// ---------------- FPS: 256 thr x 16 pts, u64 packed reduce (round-4 best) ----------------
__global__ __launch_bounds__(256) void fps_kernel(const void* __restrict__ xyz,
        float* __restrict__ nxf, void* __restrict__ out, const int* __restrict__ flag){
    __shared__ float4 pts[NN];     // 64 KB
    __shared__ int sidx[SS];
    __shared__ unsigned long long skey[2][4];
    const bool F = (*flag != 0);
    const int b = blockIdx.x, t = threadIdx.x, lane = t & 63, w = t >> 6;
    float px[16], py[16], pz[16], mind[16];
#pragma unroll
    for (int j = 0; j < 16; j++){
        int i = j*256 + t;
        float X = ld(xyz, (size_t)(b*NN+i)*3+0, F);
        float Y = ld(xyz, (size_t)(b*NN+i)*3+1, F);
        float Z = ld(xyz, (size_t)(b*NN+i)*3+2, F);
        px[j] = X; py[j] = Y; pz[j] = Z; mind[j] = 1e10f;
        pts[i] = make_float4(X, Y, Z, 0.f);
    }
    if (t == 0) sidx[0] = 0;
    __syncthreads();
    float4 q = pts[0];
    for (int s = 1; s < SS; s++){
        float bd = -1.f; int bi = 0;
#pragma unroll
        for (int j = 0; j < 16; j++){
            float dx = __fsub_rn(px[j], q.x);
            float dy = __fsub_rn(py[j], q.y);
            float dz = __fsub_rn(pz[j], q.z);
            float d  = __fadd_rn(__fadd_rn(__fmul_rn(dx,dx), __fmul_rn(dy,dy)), __fmul_rn(dz,dz));
            float m = fminf(mind[j], d); mind[j] = m;
            if (m > bd){ bd = m; bi = j*256 + t; }   // ascending index -> strict > keeps first
        }
        // pack: max d, tie -> min index (d>=0 so float bits order as uint)
        unsigned long long key = ((unsigned long long)__float_as_uint(bd) << 32)
                               | (unsigned)(~bi);
#pragma unroll
        for (int off = 1; off < 64; off <<= 1){
            unsigned long long o = __shfl_xor(key, off);
            if (o > key) key = o;
        }
        const int par = s & 1;
        if (lane == 0) skey[par][w] = key;
        __syncthreads();
        unsigned long long k0 = skey[par][0], k1 = skey[par][1];
        unsigned long long k2 = skey[par][2], k3 = skey[par][3];
        if (k1 > k0) k0 = k1;
        if (k3 > k2) k2 = k3;
        if (k2 > k0) k0 = k2;
        int ix = (int)(~(unsigned)(k0 & 0xffffffffull));
        if (t == 0) sidx[s] = ix;
        q = pts[ix];
    }
    __syncthreads();
    const size_t o1 = (size_t)BB*SS*128;
    for (int s2 = t; s2 < SS; s2 += 256){
        int i = sidx[s2];
        float4 p = pts[i];
        nxf[(b*SS+s2)*3+0] = p.x; nxf[(b*SS+s2)*3+1] = p.y; nxf[(b*SS+s2)*3+2] = p.z;
        st(out, o1 + (size_t)(b*SS+s2)*3+0, p.x, F);
        st(out, o1 + (size_t)(b*SS+s2)*3+1, p.y, F);
        st(out, o1 + (size_t)(b*SS+s2)*3+2, p.z, F);
    }
}

// ---------------- ball query v2: ballot-based parallel first-k ----------------
// wave per center; chunk c tests points c*64+lane; first-32-in-index-order preserved.
__global__ __launch_bounds__(512) void ball_kernel(const void* __restrict__ xyz,
        const float* __restrict__ nxf, int* __restrict__ idx, const int* __restrict__ flag){
    __shared__ float sx[NN], sy[NN], sz[NN];
    const bool F = (*flag != 0);
    const int b = blockIdx.x, t = threadIdx.x, lane = t & 63, w = t >> 6;
    for (int i = t; i < NN; i += 512){
        sx[i] = ld(xyz, (size_t)(b*NN+i)*3+0, F);
        sy[i] = ld(xyz, (size_t)(b*NN+i)*3+1, F);
        sz[i] = ld(xyz, (size_t)(b*NN+i)*3+2, F);
    }
    __syncthreads();
    const float R2 = 0.2f*0.2f;
    const unsigned long long below = (lane == 63) ? ~0ull >> 1
                                   : ((1ull << lane) - 1ull);
#pragma unroll
    for (int cc = 0; cc < 4; cc++){
        const int s = blockIdx.y*32 + w*4 + cc;
        const float px = nxf[(b*SS+s)*3+0];
        const float py = nxf[(b*SS+s)*3+1];
        const float pz = nxf[(b*SS+s)*3+2];
        int* op = idx + (size_t)(b*SS+s)*KNS;
        int cnt = 0;
        for (int c = 0; c < 64; c++){
            const int i = c*64 + lane;
            float dx = __fsub_rn(px, sx[i]);
            float dy = __fsub_rn(py, sy[i]);
            float dz = __fsub_rn(pz, sz[i]);
            float d2 = __fadd_rn(__fadd_rn(__fmul_rn(dx,dx), __fmul_rn(dy,dy)), __fmul_rn(dz,dz));
            const bool hit = (d2 < R2);
            unsigned long long m = __ballot(hit);
            if (hit){
                int pos = cnt + __popcll(m & below);
                if (pos < KNS) op[pos] = i;
            }
            cnt += __popcll(m);
            if (cnt >= KNS) break;
        }
        if (lane < KNS && lane >= cnt) op[lane] = -1;
    }
}

// ---------------- BN1 stats: register outer-products ----------------
__global__ __launch_bounds__(256) void bn1_stats(const void* __restrict__ xyz,
        const int* __restrict__ idx, const void* __restrict__ fpt, double* __restrict__ M,
        const int* __restrict__ flag){
    __shared__ float sfp[24];
    const bool F = (*flag != 0);
    const int t = threadIdx.x, lane = t & 63;
    if (t < 24) sfp[t] = ld(fpt, t, F);
    __syncthreads();
    float acc[105];
#pragma unroll
    for (int q = 0; q < 105; q++) acc[q] = 0.f;
    for (int it = 0; it < 8; it++){
        const int row = blockIdx.x*2048 + it*256 + t;
        const int b = row >> 15;
        const int id = idx[row];
        float gx = 0.f, gy = 0.f, gz = 0.f;
        if (id >= 0){
            gx = ld(xyz, (size_t)(b*NN+id)*3+0, F);
            gy = ld(xyz, (size_t)(b*NN+id)*3+1, F);
            gz = ld(xyz, (size_t)(b*NN+id)*3+2, F);
        }
#pragma unroll
        for (int v = 0; v < 8; v++){
            float fxv = sfp[v*3+0], fyv = sfp[v*3+1], fzv = sfp[v*3+2];
            float ax = gx - fxv, ay = gy - fyv, az = gz - fzv;
            float eu = sqrtf(ax*ax + ay*ay + az*az);
            float fv[14];
            fv[0] = -ax; fv[1] = -ay; fv[2] = -az;
            fv[3] =  ax; fv[4] =  ay; fv[5] =  az;
            fv[6] = eu;  fv[7] = gx;  fv[8] = gy; fv[9] = gz;
            fv[10] = fxv; fv[11] = fyv; fv[12] = fzv; fv[13] = 1.0f;
            int q = 0;
#pragma unroll
            for (int i = 0; i < 14; i++)
#pragma unroll
                for (int j = i; j < 14; j++){
                    acc[q] = fmaf(fv[i], fv[j], acc[q]);
                    q++;
                }
        }
    }
#pragma unroll
    for (int q = 0; q < 105; q++){
        float s = acc[q];
#pragma unroll
        for (int off = 1; off < 64; off <<= 1) s += __shfl_xor(s, off);
        if (lane == 0) atomicAdd(&M[q], (double)s);
    }
}

// ---------------- BN1 finalize ----------------
__global__ __launch_bounds__(128) void bn1_final(const double* __restrict__ M,
        const void* __restrict__ w10, const void* __restrict__ b10,
        const void* __restrict__ g1, const void* __restrict__ bt1, float* __restrict__ bn1,
        const int* __restrict__ flag){
    __shared__ double Mm[14][14];
    __shared__ double mv[14];
    const bool F = (*flag != 0);
    const int t = threadIdx.x;
    if (t < 105){
        int e = t, i = 0, off = 0;
        while (e - off >= 14 - i){ off += 14 - i; i++; }
        int j = i + (e - off);
        double val = M[t];
        Mm[i][j] = val; Mm[j][i] = val;
    }
    __syncthreads();
    const double K = 1048576.0;
    if (t < 14) mv[t] = Mm[t][13] / K;
    __syncthreads();
    if (t < 64){
        double wc[13];
        for (int i = 0; i < 13; i++) wc[i] = (double)ld(w10, i*64+t, F);
        double mean = (double)ld(b10, t, F);
        for (int i = 0; i < 13; i++) mean += mv[i]*wc[i];
        double var = 0.0;
        for (int i = 0; i < 13; i++)
            for (int j = 0; j < 13; j++)
                var += wc[i]*wc[j]*(Mm[i][j]/K - mv[i]*mv[j]);
        float sc = ld(g1, t, F) / sqrtf((float)var + 1e-5f);
        bn1[t] = sc;
        bn1[64+t] = ld(bt1, t, F) - (float)mean * sc;
    }
}

// ---------------- m1: MFMA phase B (3-pass bf16 hi/lo), per-wave pipeline ----------------
__global__ __launch_bounds__(256) void m1_kernel(
        const void* __restrict__ xyz, const void* __restrict__ f, const void* __restrict__ fpt,
        const void* __restrict__ w10, const void* __restrict__ b10,
        const void* __restrict__ w11, const void* __restrict__ b11,
        const float* __restrict__ nxf, const int* __restrict__ idx,
        const float* __restrict__ bn1, float* __restrict__ agg, const int* __restrict__ flag){
    __shared__ short sthi[4*2*8*72];
    __shared__ short stlo[4*2*8*72];
    __shared__ float gfb[4*2*80];
    const bool F = (*flag != 0);
    const int t = threadIdx.x, lane = t & 63, w = t >> 6;
    const int kq = lane >> 4, cn = lane & 15;

    short8 Bh[2][5], Bl[2][5];
#pragma unroll
    for (int ks = 0; ks < 2; ks++)
#pragma unroll
    for (int nt = 0; nt < 5; nt++){
        short8 bh, bl;
#pragma unroll
        for (int j = 0; j < 8; j++){
            int k = ks*32 + kq*8 + j;
            int c = nt*16 + cn;
            float wv = (c < C1) ? ld(w11, (size_t)k*C1 + c, F) : 0.f;
            unsigned short h = f2us(wv);
            unsigned short l2 = f2us(wv - us2f(h));
            bh[j] = (short)h; bl[j] = (short)l2;
        }
        Bh[ks][nt] = bh; Bl[ks][nt] = bl;
    }
    float binit[5];
#pragma unroll
    for (int nt = 0; nt < 5; nt++){
        int c = nt*16 + cn;
        binit[nt] = (c < C1) ? ld(b11, c, F) : 0.f;
    }
    float W10c[13];
#pragma unroll
    for (int i = 0; i < 13; i++) W10c[i] = ld(w10, i*64+lane, F);
    const float b10v = ld(b10, lane, F);
    const float sc1 = bn1[lane], sh1 = bn1[64+lane];
    float fx[8], fy[8], fz[8];
#pragma unroll
    for (int v = 0; v < 8; v++){
        fx[v] = ld(fpt, v*3+0, F); fy[v] = ld(fpt, v*3+1, F); fz[v] = ld(fpt, v*3+2, F);
    }
    const int quad = lane >> 4;
    const int rr = quad >> 1;
    const int hh = quad & 1;
    const int mA = lane & 15;
    const int rA = mA >> 3, vA = mA & 7;

    const int wid = blockIdx.x*4 + w;
    for (int p = 0; p < 16; p++){
        const int rowbase = wid*32 + p*2;
        int ids[2];
#pragma unroll
        for (int r = 0; r < 2; r++){
            const int row = rowbase + r;
            const int b = row >> 15, s = (row >> 5) & 1023;
            const int id = idx[row];
            ids[r] = id;
            float gx = 0.f, gy = 0.f, gz = 0.f, fv0 = 0.f, fv1 = 0.f;
            if (id >= 0){
                gx = ld(xyz, (size_t)(b*NN+id)*3+0, F);
                gy = ld(xyz, (size_t)(b*NN+id)*3+1, F);
                gz = ld(xyz, (size_t)(b*NN+id)*3+2, F);
                if (lane >= 6) fv0 = ld(f, (size_t)(b*NN+id)*64 + (lane-6), F);
                if (lane < 6)  fv1 = ld(f, (size_t)(b*NN+id)*64 + (58+lane), F);
            }
            const float nxx = nxf[(b*SS+s)*3+0], nxy = nxf[(b*SS+s)*3+1], nxz = nxf[(b*SS+s)*3+2];
            float gf0;
            if (lane == 0) gf0 = gx; else if (lane == 1) gf0 = gy; else if (lane == 2) gf0 = gz;
            else if (lane == 3) gf0 = gx - nxx; else if (lane == 4) gf0 = gy - nxy;
            else if (lane == 5) gf0 = gz - nxz; else gf0 = fv0;
            gfb[w*160 + r*80 + lane] = gf0;
            if (lane < 6)       gfb[w*160 + r*80 + 64 + lane] = fv1;
            else if (lane < 16) gfb[w*160 + r*80 + 64 + lane] = 0.f;
            const int sb = ((w*2 + r)*8)*72 + lane;
#pragma unroll
            for (int v = 0; v < 8; v++){
                float ax = gx - fx[v], ay = gy - fy[v], az = gz - fz[v];
                float eu = sqrtf(ax*ax + ay*ay + az*az);
                float z = b10v;
                z = fmaf(-ax, W10c[0], z); z = fmaf(-ay, W10c[1], z); z = fmaf(-az, W10c[2], z);
                z = fmaf( ax, W10c[3], z); z = fmaf( ay, W10c[4], z); z = fmaf( az, W10c[5], z);
                z = fmaf( eu, W10c[6], z);
                z = fmaf( gx, W10c[7], z); z = fmaf( gy, W10c[8], z); z = fmaf( gz, W10c[9], z);
                z = fmaf(fx[v], W10c[10], z); z = fmaf(fy[v], W10c[11], z); z = fmaf(fz[v], W10c[12], z);
                float a1 = fmaxf(fmaf(z, sc1, sh1), 0.f);
                unsigned short h = f2us(a1);
                unsigned short l2 = f2us(a1 - us2f(h));
                sthi[sb + v*72] = (short)h;
                stlo[sb + v*72] = (short)l2;
            }
        }
        f32x4 acc[5];
#pragma unroll
        for (int nt = 0; nt < 5; nt++){
            f32x4 a; a[0] = binit[nt]; a[1] = binit[nt]; a[2] = binit[nt]; a[3] = binit[nt];
            acc[nt] = a;
        }
        const int aoff = ((w*2 + rA)*8 + vA)*72 + kq*8;
#pragma unroll
        for (int ks = 0; ks < 2; ks++){
            short8 ahi = *(const short8*)&sthi[aoff + ks*32];
            short8 alo = *(const short8*)&stlo[aoff + ks*32];
#pragma unroll
            for (int nt = 0; nt < 5; nt++){
                acc[nt] = __builtin_amdgcn_mfma_f32_16x16x32_bf16(ahi, Bh[ks][nt], acc[nt], 0, 0, 0);
                acc[nt] = __builtin_amdgcn_mfma_f32_16x16x32_bf16(alo, Bh[ks][nt], acc[nt], 0, 0, 0);
                acc[nt] = __builtin_amdgcn_mfma_f32_16x16x32_bf16(ahi, Bl[ks][nt], acc[nt], 0, 0, 0);
            }
        }
        const bool msk = ((rr == 0 ? ids[0] : ids[1]) < 0);
#pragma unroll
        for (int nt = 0; nt < 5; nt++){
            const int col = nt*16 + cn;
            float gfv = gfb[w*160 + rr*80 + col];
            f32x4 a = acc[nt];
            float p0 = a[0]*gfv, p1 = a[1]*gfv, p2 = a[2]*gfv, p3 = a[3]*gfv;
            float mx = fmaxf(fmaxf(p0, p1), fmaxf(p2, p3));
            mx = fmaxf(mx, __shfl_xor(mx, 16));
            float e0 = __expf(p0 - mx), e1 = __expf(p1 - mx);
            float e2 = __expf(p2 - mx), e3 = __expf(p3 - mx);
            float den4 = (e0 + e1) + (e2 + e3);
            float num4 = fmaf(e3, p3, fmaf(e2, p2, fmaf(e1, p1, e0*p0)));
            float den = den4 + __shfl_xor(den4, 16);
            float num = num4 + __shfl_xor(num4, 16);
            float outv = num / den;
            if (hh == 0 && col < C1){
                agg[(size_t)(rowbase + rr)*C1 + col] = msk ? 0.f : outv;
            }
        }
    }
}

// ---------------- prep1: raw f32 weights (no bn2 dependency) ----------------
__global__ __launch_bounds__(256) void prep1_kernel(
        const void* __restrict__ w20, const void* __restrict__ w21,
        const void* __restrict__ rw, const void* __restrict__ b20,
        const void* __restrict__ b21, const void* __restrict__ rb,
        float* __restrict__ w20r, float* __restrict__ w21f, float* __restrict__ rwf,
        float* __restrict__ b20r, float* __restrict__ bof, const int* __restrict__ flag){
    const bool F = (*flag != 0);
    int e = blockIdx.x*256 + threadIdx.x;
    if (e < 8960){ w20r[e] = ld(w20, e, F); return; }
    int e2 = e - 8960;
    if (e2 < 16384){ w21f[e2] = ld(w21, e2, F); return; }
    int e3 = e2 - 16384;
    if (e3 < 8192){ rwf[e3] = ld(rw, e3, F); return; }
    int e4 = e3 - 8192;
    if (e4 < 128){
        b20r[e4] = ld(b20, e4, F);
        bof[e4]  = ld(b21, e4, F) + ld(rb, e4, F);
    }
}

// ---------------- BN2 stats: tiled GEMM, agg read once ----------------
__global__ __launch_bounds__(256) void bn2_stats(const float* __restrict__ agg,
        const float* __restrict__ w20r, const float* __restrict__ b20r,
        double* __restrict__ sums){
    __shared__ float aggT[70*65];   // [k][r]
    const int t = threadIdx.x, lane = t & 63;
    const int wbase = __builtin_amdgcn_readfirstlane((t >> 6) << 5);
    float binit[32];
#pragma unroll
    for (int j = 0; j < 32; j++) binit[j] = b20r[wbase + j];
    float accs[32], accq[32];
#pragma unroll
    for (int j = 0; j < 32; j++){ accs[j] = 0.f; accq[j] = 0.f; }
    for (int it = 0; it < 8; it++){
        const int rowbase = blockIdx.x*512 + it*64;
        __syncthreads();
        for (int e = t; e < 70*64; e += 256){
            int r = e / 70, k = e - r*70;
            aggT[k*65 + r] = agg[(size_t)rowbase*70 + e];
        }
        __syncthreads();
        float z[32];
#pragma unroll
        for (int j = 0; j < 32; j++) z[j] = binit[j];
#pragma unroll 2
        for (int k = 0; k < 70; k++){
            float av = aggT[k*65 + lane];
            const float* wr = w20r + k*128 + wbase;
#pragma unroll
            for (int j = 0; j < 32; j++) z[j] = fmaf(av, wr[j], z[j]);
        }
#pragma unroll
        for (int j = 0; j < 32; j++){
            accs[j] += z[j];
            accq[j] = fmaf(z[j], z[j], accq[j]);
        }
    }
#pragma unroll
    for (int j = 0; j < 32; j++){
        float s = accs[j], q = accq[j];
#pragma unroll
        for (int off = 1; off < 64; off <<= 1){
            s += __shfl_xor(s, off);
            q += __shfl_xor(q, off);
        }
        if (lane == 0){
            atomicAdd(&sums[wbase + j], (double)s);
            atomicAdd(&sums[128 + wbase + j], (double)q);
        }
    }
}

// ---------------- BN2 finalize ----------------
__global__ void bn2_final(const double* __restrict__ sums, const void* __restrict__ g2,
        const void* __restrict__ bt2, float* __restrict__ bn2, const int* __restrict__ flag){
    const bool F = (*flag != 0);
    int t = threadIdx.x; // 128
    const double K = 131072.0;
    double mean = sums[t] / K;
    double var = sums[128+t] / K - mean*mean;
    float sc = ld(g2, t, F) / sqrtf((float)var + 1e-5f);
    bn2[t] = sc;
    bn2[128+t] = ld(bt2, t, F) - (float)mean * sc;
}

// ---------------- prep2: fold bn2 into w20 ----------------
__global__ __launch_bounds__(256) void prep2_kernel(
        const float* __restrict__ w20r, const float* __restrict__ b20r,
        const float* __restrict__ bn2,
        float* __restrict__ w20f, float* __restrict__ b20f){
    int e = blockIdx.x*256 + threadIdx.x;
    if (e < 8960){ w20f[e] = w20r[e] * bn2[e & 127]; return; }
    int e2 = e - 8960;
    if (e2 < 128){ b20f[e2] = b20r[e2]*bn2[e2] + bn2[128+e2]; }
}

// ---------------- final: lane=row, regs=32 channels/wave ----------------
__global__ __launch_bounds__(256) void final_kernel(
        const float* __restrict__ agg, const void* __restrict__ f, const int* __restrict__ idx,
        const float* __restrict__ w20f, const float* __restrict__ b20f,
        const float* __restrict__ w21f, const float* __restrict__ rwf,
        const float* __restrict__ bof,
        void* __restrict__ out, const int* __restrict__ flag){
    __shared__ float aggT[70*65];
    __shared__ float gfs[64*65];
    __shared__ float wmids[128*64];
    __shared__ float obuf[256];
    const bool F = (*flag != 0);
    const int t = threadIdx.x, lane = t & 63;
    const int wbase = __builtin_amdgcn_readfirstlane((t >> 6) << 5);
    const int rowbase = blockIdx.x * 64;
    for (int e = t; e < 70*64; e += 256){
        int r = e / 70, k = e - r*70;
        aggT[k*65 + r] = agg[(size_t)rowbase*70 + e];
    }
    for (int e = t; e < 64*64; e += 256){
        int r = e >> 6, cin = e & 63;
        int id = idx[rowbase + r];
        int b = (rowbase + r) >> 15;
        gfs[cin*65 + r] = (id >= 0) ? ld(f, (size_t)(b*NN+id)*64 + cin, F) : 0.f;
    }
    __syncthreads();
    float acc[32];
#pragma unroll
    for (int j = 0; j < 32; j++) acc[j] = b20f[wbase + j];
#pragma unroll 2
    for (int k = 0; k < 70; k++){
        float av = aggT[k*65 + lane];
        const float* wr = w20f + k*128 + wbase;
#pragma unroll
        for (int j = 0; j < 32; j++) acc[j] = fmaf(av, wr[j], acc[j]);
    }
#pragma unroll
    for (int j = 0; j < 32; j++)
        wmids[(wbase + j)*64 + lane] = fmaxf(acc[j], 0.f);
    __syncthreads();
    float acc2[32];
#pragma unroll
    for (int j = 0; j < 32; j++) acc2[j] = bof[wbase + j];
#pragma unroll 2
    for (int k = 0; k < 128; k++){
        float wv = wmids[k*64 + lane];
        const float* wr = w21f + k*128 + wbase;
#pragma unroll
        for (int j = 0; j < 32; j++) acc2[j] = fmaf(wv, wr[j], acc2[j]);
    }
#pragma unroll 2
    for (int k = 0; k < 64; k++){
        float gv = gfs[k*65 + lane];
        const float* wr = rwf + k*128 + wbase;
#pragma unroll
        for (int j = 0; j < 32; j++) acc2[j] = fmaf(gv, wr[j], acc2[j]);
    }
#pragma unroll
    for (int j = 0; j < 32; j++){
        float x = acc2[j];
        float y = 0.5f * x * (1.f + erff(x * 0.70710678118654752f));
#pragma unroll
        for (int off = 1; off < 32; off <<= 1)
            y = fmaxf(y, __shfl_xor(y, off));
        if ((lane & 31) == 0) obuf[(lane >> 5)*128 + wbase + j] = y;
    }
    __syncthreads();
    st(out, (size_t)blockIdx.x*256 + t, obuf[t], F);
}

extern "C" void kernel_launch(void* const* d_in, const int* in_sizes, int n_in,
                              void* d_out, int out_size, void* d_ws, size_t ws_size,
                              hipStream_t stream){
    const void* xyz = d_in[0];
    const void* f   = d_in[1];
    const void* fpt = d_in[2];
    const void* w10 = d_in[3];
    const void* b10 = d_in[4];
    const void* g1  = d_in[5];
    const void* bt1 = d_in[6];
    const void* w11 = d_in[7];
    const void* b11 = d_in[8];
    const void* w20 = d_in[9];
    const void* b20 = d_in[10];
    const void* g2  = d_in[11];
    const void* bt2 = d_in[12];
    const void* w21 = d_in[13];
    const void* b21 = d_in[14];
    const void* rw  = d_in[15];
    const void* rb  = d_in[16];

    char* ws = (char*)d_ws;
    float*  nxf  = (float*) (ws + 0);
    int*    idx  = (int*)   (ws + 65536);
    double* M    = (double*)(ws + 655360);
    float*  bn1  = (float*) (ws + 786432);
    double* sums = (double*)(ws + 917504);
    float*  bn2  = (float*) (ws + 1048576);
    int*    flag = (int*)   (ws + 1050624);
    float*  w20f = (float*) (ws + 1114112);
    float*  w21f = (float*) (ws + 1179648);
    float*  rwf  = (float*) (ws + 1245184);
    float*  b20f = (float*) (ws + 1277952);
    float*  bof  = (float*) (ws + 1278464);
    float*  w20r = (float*) (ws + 1310720);
    float*  b20r = (float*) (ws + 1441792);
    float*  agg  = (float*) (ws + 2097152);

    init_kernel<<<1, 256, 0, stream>>>(xyz, M, sums, flag);
    fps_kernel<<<4, 256, 0, stream>>>(xyz, nxf, d_out, flag);
    ball_kernel<<<dim3(4, 32), 512, 0, stream>>>(xyz, nxf, idx, flag);
    prep1_kernel<<<132, 256, 0, stream>>>(w20, w21, rw, b20, b21, rb,
                                          w20r, w21f, rwf, b20r, bof, flag);
    bn1_stats<<<64, 256, 0, stream>>>(xyz, idx, fpt, M, flag);
    bn1_final<<<1, 128, 0, stream>>>(M, w10, b10, g1, bt1, bn1, flag);
    m1_kernel<<<1024, 256, 0, stream>>>(xyz, f, fpt, w10, b10, w11, b11, nxf, idx, bn1, agg, flag);
    bn2_stats<<<256, 256, 0, stream>>>(agg, w20r, b20r, sums);
    bn2_final<<<1, 128, 0, stream>>>(sums, g2, bt2, bn2, flag);
    prep2_kernel<<<36, 256, 0, stream>>>(w20r, b20r, bn2, w20f, b20f);
    final_kernel<<<2048, 256, 0, stream>>>(agg, f, idx, w20f, b20f, w21f, rwf, bof, d_out, flag);
}

// Round 7
// 1356.867 us; speedup vs baseline: 1.4724x; 1.0808x over previous
//
#include <hip/hip_runtime.h>
#include <hip/hip_bf16.h>
#include <math.h>

typedef __hip_bfloat16 bf16;
typedef __attribute__((ext_vector_type(8))) short short8;
typedef __attribute__((ext_vector_type(4))) float f32x4;

#define BB  4
#define NN  4096
#define SS  1024
#define KNS 32
#define C1  70

__device__ __forceinline__ float b2f(bf16 x){ return __bfloat162float(x); }

__device__ __forceinline__ float ld(const void* p, size_t i, bool F){
    return F ? ((const float*)p)[i] : __bfloat162float(((const bf16*)p)[i]);
}
__device__ __forceinline__ void st(void* p, size_t i, float v, bool F){
    if (F) ((float*)p)[i] = v; else ((bf16*)p)[i] = __float2bfloat16(v);
}
__device__ __forceinline__ unsigned short f2us(float x){
    __hip_bfloat16 h = __float2bfloat16(x);
    return *reinterpret_cast<unsigned short*>(&h);
}
__device__ __forceinline__ float us2f(unsigned short u){
    return __uint_as_float(((unsigned)u) << 16);
}

// ---------------- init: dtype detect + zero stats ----------------
__global__ void init_kernel(const void* xyz, double* __restrict__ M,
                            double* __restrict__ sums, int* __restrict__ flag){
    __shared__ int cnt;
    const int t = threadIdx.x;
    if (t == 0) cnt = 0;
    if (t < 105) M[t] = 0.0;
    if (t < 256) sums[t] = 0.0;
    __syncthreads();
    int c = 0;
    for (int i = t; i < 2048; i += 256){
        float v = __bfloat162float(((const bf16*)xyz)[i]);
        if (!(fabsf(v) <= 1.5f)) c++;   // catches NaN too
    }
    atomicAdd(&cnt, c);
    __syncthreads();
    if (t == 0) *flag = (cnt > 10) ? 1 : 0;
}

// ---------------- FPS: 256 thr x 16 pts, u64 packed reduce ----------------
__global__ __launch_bounds__(256) void fps_kernel(const void* __restrict__ xyz,
        float* __restrict__ nxf, void* __restrict__ out, const int* __restrict__ flag){
    __shared__ float4 pts[NN];     // 64 KB
    __shared__ int sidx[SS];
    __shared__ unsigned long long skey[2][4];
    const bool F = (*flag != 0);
    const int b = blockIdx.x, t = threadIdx.x, lane = t & 63, w = t >> 6;
    float px[16], py[16], pz[16], mind[16];
#pragma unroll
    for (int j = 0; j < 16; j++){
        int i = j*256 + t;
        float X = ld(xyz, (size_t)(b*NN+i)*3+0, F);
        float Y = ld(xyz, (size_t)(b*NN+i)*3+1, F);
        float Z = ld(xyz, (size_t)(b*NN+i)*3+2, F);
        px[j] = X; py[j] = Y; pz[j] = Z; mind[j] = 1e10f;
        pts[i] = make_float4(X, Y, Z, 0.f);
    }
    if (t == 0) sidx[0] = 0;
    __syncthreads();
    float4 q = pts[0];
    for (int s = 1; s < SS; s++){
        float bd = -1.f; int bi = 0;
#pragma unroll
        for (int j = 0; j < 16; j++){
            float dx = __fsub_rn(px[j], q.x);
            float dy = __fsub_rn(py[j], q.y);
            float dz = __fsub_rn(pz[j], q.z);
            float d  = __fadd_rn(__fadd_rn(__fmul_rn(dx,dx), __fmul_rn(dy,dy)), __fmul_rn(dz,dz));
            float m = fminf(mind[j], d); mind[j] = m;
            if (m > bd){ bd = m; bi = j*256 + t; }   // ascending index -> strict > keeps first
        }
        unsigned long long key = ((unsigned long long)__float_as_uint(bd) << 32)
                               | (unsigned)(~bi);
#pragma unroll
        for (int off = 1; off < 64; off <<= 1){
            unsigned long long o = __shfl_xor(key, off);
            if (o > key) key = o;
        }
        const int par = s & 1;
        if (lane == 0) skey[par][w] = key;
        __syncthreads();
        unsigned long long k0 = skey[par][0], k1 = skey[par][1];
        unsigned long long k2 = skey[par][2], k3 = skey[par][3];
        if (k1 > k0) k0 = k1;
        if (k3 > k2) k2 = k3;
        if (k2 > k0) k0 = k2;
        int ix = (int)(~(unsigned)(k0 & 0xffffffffull));
        if (t == 0) sidx[s] = ix;
        q = pts[ix];
    }
    __syncthreads();
    const size_t o1 = (size_t)BB*SS*128;
    for (int s2 = t; s2 < SS; s2 += 256){
        int i = sidx[s2];
        float4 p = pts[i];
        nxf[(b*SS+s2)*3+0] = p.x; nxf[(b*SS+s2)*3+1] = p.y; nxf[(b*SS+s2)*3+2] = p.z;
        st(out, o1 + (size_t)(b*SS+s2)*3+0, p.x, F);
        st(out, o1 + (size_t)(b*SS+s2)*3+1, p.y, F);
        st(out, o1 + (size_t)(b*SS+s2)*3+2, p.z, F);
    }
}

// ---------------- ball query: ballot-based parallel first-k ----------------
__global__ __launch_bounds__(512) void ball_kernel(const void* __restrict__ xyz,
        const float* __restrict__ nxf, int* __restrict__ idx, const int* __restrict__ flag){
    __shared__ float sx[NN], sy[NN], sz[NN];
    const bool F = (*flag != 0);
    const int b = blockIdx.x, t = threadIdx.x, lane = t & 63, w = t >> 6;
    for (int i = t; i < NN; i += 512){
        sx[i] = ld(xyz, (size_t)(b*NN+i)*3+0, F);
        sy[i] = ld(xyz, (size_t)(b*NN+i)*3+1, F);
        sz[i] = ld(xyz, (size_t)(b*NN+i)*3+2, F);
    }
    __syncthreads();
    const float R2 = 0.2f*0.2f;
    const unsigned long long below = (lane == 63) ? ~0ull >> 1
                                   : ((1ull << lane) - 1ull);
#pragma unroll
    for (int cc = 0; cc < 4; cc++){
        const int s = blockIdx.y*32 + w*4 + cc;
        const float px = nxf[(b*SS+s)*3+0];
        const float py = nxf[(b*SS+s)*3+1];
        const float pz = nxf[(b*SS+s)*3+2];
        int* op = idx + (size_t)(b*SS+s)*KNS;
        int cnt = 0;
        for (int c = 0; c < 64; c++){
            const int i = c*64 + lane;
            float dx = __fsub_rn(px, sx[i]);
            float dy = __fsub_rn(py, sy[i]);
            float dz = __fsub_rn(pz, sz[i]);
            float d2 = __fadd_rn(__fadd_rn(__fmul_rn(dx,dx), __fmul_rn(dy,dy)), __fmul_rn(dz,dz));
            const bool hit = (d2 < R2);
            unsigned long long m = __ballot(hit);
            if (hit){
                int pos = cnt + __popcll(m & below);
                if (pos < KNS) op[pos] = i;
            }
            cnt += __popcll(m);
            if (cnt >= KNS) break;
        }
        if (lane < KNS && lane >= cnt) op[lane] = -1;
    }
}

// ---------------- BN1 stats: 11-feature register outer-products (66 moments) ----------------
__global__ __launch_bounds__(256) void bn1_stats(const void* __restrict__ xyz,
        const int* __restrict__ idx, const void* __restrict__ fpt, double* __restrict__ M,
        const int* __restrict__ flag){
    __shared__ float sfp[24];
    const bool F = (*flag != 0);
    const int t = threadIdx.x, lane = t & 63;
    if (t < 24) sfp[t] = ld(fpt, t, F);
    __syncthreads();
    float acc[66];
#pragma unroll
    for (int q = 0; q < 66; q++) acc[q] = 0.f;
    for (int it = 0; it < 4; it++){
        const int row = blockIdx.x*1024 + it*256 + t;
        const int b = row >> 15;
        const int id = idx[row];
        float gx = 0.f, gy = 0.f, gz = 0.f;
        if (id >= 0){
            gx = ld(xyz, (size_t)(b*NN+id)*3+0, F);
            gy = ld(xyz, (size_t)(b*NN+id)*3+1, F);
            gz = ld(xyz, (size_t)(b*NN+id)*3+2, F);
        }
#pragma unroll
        for (int v = 0; v < 8; v++){
            float fxv = sfp[v*3+0], fyv = sfp[v*3+1], fzv = sfp[v*3+2];
            float ax = gx - fxv, ay = gy - fyv, az = gz - fzv;
            float eu = sqrtf(ax*ax + ay*ay + az*az);
            float f11[11];
            f11[0] = ax; f11[1] = ay; f11[2] = az; f11[3] = eu;
            f11[4] = gx; f11[5] = gy; f11[6] = gz;
            f11[7] = fxv; f11[8] = fyv; f11[9] = fzv; f11[10] = 1.0f;
            int q = 0;
#pragma unroll
            for (int i = 0; i < 11; i++)
#pragma unroll
                for (int j = i; j < 11; j++){
                    acc[q] = fmaf(f11[i], f11[j], acc[q]);
                    q++;
                }
        }
    }
#pragma unroll
    for (int q = 0; q < 66; q++){
        float s = acc[q];
#pragma unroll
        for (int off = 1; off < 64; off <<= 1) s += __shfl_xor(s, off);
        if (lane == 0) atomicAdd(&M[q], (double)s);
    }
}

// ---------------- BN1 finalize (expand 11-feature moments to 14x14) ----------------
__global__ __launch_bounds__(128) void bn1_final(const double* __restrict__ M,
        const void* __restrict__ w10, const void* __restrict__ b10,
        const void* __restrict__ g1, const void* __restrict__ bt1, float* __restrict__ bn1,
        const int* __restrict__ flag){
    __shared__ double Ms[11][11];
    __shared__ double mv14[14];
    const bool F = (*flag != 0);
    const int t = threadIdx.x;
    if (t < 66){
        int e = t, i = 0, off = 0;
        while (e - off >= 11 - i){ off += 11 - i; i++; }
        int j = i + (e - off);
        double val = M[t];
        Ms[i][j] = val; Ms[j][i] = val;
    }
    __syncthreads();
    const double K = 1048576.0;
    // coc feature i14 -> (sign, base in 11-space)
    const int    bi14[14] = {0,1,2, 0,1,2, 3, 4,5,6, 7,8,9, 10};
    const double sg14[14] = {-1,-1,-1, 1,1,1, 1, 1,1,1, 1,1,1, 1};
    if (t < 14) mv14[t] = sg14[t] * Ms[bi14[t]][10] / K;
    __syncthreads();
    if (t < 64){
        double wc[13];
        for (int i = 0; i < 13; i++) wc[i] = (double)ld(w10, i*64+t, F);
        double mean = (double)ld(b10, t, F);
        for (int i = 0; i < 13; i++) mean += mv14[i]*wc[i];
        double var = 0.0;
        for (int i = 0; i < 13; i++)
            for (int j = 0; j < 13; j++){
                double mij = sg14[i]*sg14[j]*Ms[bi14[i]][bi14[j]]/K;
                var += wc[i]*wc[j]*(mij - mv14[i]*mv14[j]);
            }
        float sc = ld(g1, t, F) / sqrtf((float)var + 1e-5f);
        bn1[t] = sc;
        bn1[64+t] = ld(bt1, t, F) - (float)mean * sc;
    }
}

// ---------------- m1: MFMA phase B (3-pass bf16 hi/lo), per-wave pipeline ----------------
__global__ __launch_bounds__(256) void m1_kernel(
        const void* __restrict__ xyz, const void* __restrict__ f, const void* __restrict__ fpt,
        const void* __restrict__ w10, const void* __restrict__ b10,
        const void* __restrict__ w11, const void* __restrict__ b11,
        const float* __restrict__ nxf, const int* __restrict__ idx,
        const float* __restrict__ bn1, float* __restrict__ agg, const int* __restrict__ flag){
    __shared__ short sthi[4*2*8*72];
    __shared__ short stlo[4*2*8*72];
    __shared__ float gfb[4*2*80];
    const bool F = (*flag != 0);
    const int t = threadIdx.x, lane = t & 63, w = t >> 6;
    const int kq = lane >> 4, cn = lane & 15;

    short8 Bh[2][5], Bl[2][5];
#pragma unroll
    for (int ks = 0; ks < 2; ks++)
#pragma unroll
    for (int nt = 0; nt < 5; nt++){
        short8 bh, bl;
#pragma unroll
        for (int j = 0; j < 8; j++){
            int k = ks*32 + kq*8 + j;
            int c = nt*16 + cn;
            float wv = (c < C1) ? ld(w11, (size_t)k*C1 + c, F) : 0.f;
            unsigned short h = f2us(wv);
            unsigned short l2 = f2us(wv - us2f(h));
            bh[j] = (short)h; bl[j] = (short)l2;
        }
        Bh[ks][nt] = bh; Bl[ks][nt] = bl;
    }
    float binit[5];
#pragma unroll
    for (int nt = 0; nt < 5; nt++){
        int c = nt*16 + cn;
        binit[nt] = (c < C1) ? ld(b11, c, F) : 0.f;
    }
    float W10c[13];
#pragma unroll
    for (int i = 0; i < 13; i++) W10c[i] = ld(w10, i*64+lane, F);
    const float b10v = ld(b10, lane, F);
    const float sc1 = bn1[lane], sh1 = bn1[64+lane];
    float fx[8], fy[8], fz[8];
#pragma unroll
    for (int v = 0; v < 8; v++){
        fx[v] = ld(fpt, v*3+0, F); fy[v] = ld(fpt, v*3+1, F); fz[v] = ld(fpt, v*3+2, F);
    }
    const int quad = lane >> 4;
    const int rr = quad >> 1;
    const int hh = quad & 1;
    const int mA = lane & 15;
    const int rA = mA >> 3, vA = mA & 7;

    const int wid = blockIdx.x*4 + w;
    for (int p = 0; p < 16; p++){
        const int rowbase = wid*32 + p*2;
        int ids[2];
#pragma unroll
        for (int r = 0; r < 2; r++){
            const int row = rowbase + r;
            const int b = row >> 15, s = (row >> 5) & 1023;
            const int id = idx[row];
            ids[r] = id;
            float gx = 0.f, gy = 0.f, gz = 0.f, fv0 = 0.f, fv1 = 0.f;
            if (id >= 0){
                gx = ld(xyz, (size_t)(b*NN+id)*3+0, F);
                gy = ld(xyz, (size_t)(b*NN+id)*3+1, F);
                gz = ld(xyz, (size_t)(b*NN+id)*3+2, F);
                if (lane >= 6) fv0 = ld(f, (size_t)(b*NN+id)*64 + (lane-6), F);
                if (lane < 6)  fv1 = ld(f, (size_t)(b*NN+id)*64 + (58+lane), F);
            }
            const float nxx = nxf[(b*SS+s)*3+0], nxy = nxf[(b*SS+s)*3+1], nxz = nxf[(b*SS+s)*3+2];
            float gf0;
            if (lane == 0) gf0 = gx; else if (lane == 1) gf0 = gy; else if (lane == 2) gf0 = gz;
            else if (lane == 3) gf0 = gx - nxx; else if (lane == 4) gf0 = gy - nxy;
            else if (lane == 5) gf0 = gz - nxz; else gf0 = fv0;
            gfb[w*160 + r*80 + lane] = gf0;
            if (lane < 6)       gfb[w*160 + r*80 + 64 + lane] = fv1;
            else if (lane < 16) gfb[w*160 + r*80 + 64 + lane] = 0.f;
            const int sb = ((w*2 + r)*8)*72 + lane;
#pragma unroll
            for (int v = 0; v < 8; v++){
                float ax = gx - fx[v], ay = gy - fy[v], az = gz - fz[v];
                float eu = sqrtf(ax*ax + ay*ay + az*az);
                float z = b10v;
                z = fmaf(-ax, W10c[0], z); z = fmaf(-ay, W10c[1], z); z = fmaf(-az, W10c[2], z);
                z = fmaf( ax, W10c[3], z); z = fmaf( ay, W10c[4], z); z = fmaf( az, W10c[5], z);
                z = fmaf( eu, W10c[6], z);
                z = fmaf( gx, W10c[7], z); z = fmaf( gy, W10c[8], z); z = fmaf( gz, W10c[9], z);
                z = fmaf(fx[v], W10c[10], z); z = fmaf(fy[v], W10c[11], z); z = fmaf(fz[v], W10c[12], z);
                float a1 = fmaxf(fmaf(z, sc1, sh1), 0.f);
                unsigned short h = f2us(a1);
                unsigned short l2 = f2us(a1 - us2f(h));
                sthi[sb + v*72] = (short)h;
                stlo[sb + v*72] = (short)l2;
            }
        }
        f32x4 acc[5];
#pragma unroll
        for (int nt = 0; nt < 5; nt++){
            f32x4 a; a[0] = binit[nt]; a[1] = binit[nt]; a[2] = binit[nt]; a[3] = binit[nt];
            acc[nt] = a;
        }
        const int aoff = ((w*2 + rA)*8 + vA)*72 + kq*8;
#pragma unroll
        for (int ks = 0; ks < 2; ks++){
            short8 ahi = *(const short8*)&sthi[aoff + ks*32];
            short8 alo = *(const short8*)&stlo[aoff + ks*32];
#pragma unroll
            for (int nt = 0; nt < 5; nt++){
                acc[nt] = __builtin_amdgcn_mfma_f32_16x16x32_bf16(ahi, Bh[ks][nt], acc[nt], 0, 0, 0);
                acc[nt] = __builtin_amdgcn_mfma_f32_16x16x32_bf16(alo, Bh[ks][nt], acc[nt], 0, 0, 0);
                acc[nt] = __builtin_amdgcn_mfma_f32_16x16x32_bf16(ahi, Bl[ks][nt], acc[nt], 0, 0, 0);
            }
        }
        const bool msk = ((rr == 0 ? ids[0] : ids[1]) < 0);
#pragma unroll
        for (int nt = 0; nt < 5; nt++){
            const int col = nt*16 + cn;
            float gfv = gfb[w*160 + rr*80 + col];
            f32x4 a = acc[nt];
            float p0 = a[0]*gfv, p1 = a[1]*gfv, p2 = a[2]*gfv, p3 = a[3]*gfv;
            float mx = fmaxf(fmaxf(p0, p1), fmaxf(p2, p3));
            mx = fmaxf(mx, __shfl_xor(mx, 16));
            float e0 = __expf(p0 - mx), e1 = __expf(p1 - mx);
            float e2 = __expf(p2 - mx), e3 = __expf(p3 - mx);
            float den4 = (e0 + e1) + (e2 + e3);
            float num4 = fmaf(e3, p3, fmaf(e2, p2, fmaf(e1, p1, e0*p0)));
            float den = den4 + __shfl_xor(den4, 16);
            float num = num4 + __shfl_xor(num4, 16);
            float outv = num / den;
            if (hh == 0 && col < C1){
                agg[(size_t)(rowbase + rr)*C1 + col] = msk ? 0.f : outv;
            }
        }
    }
}

// ---------------- weight fragment packing helper ----------------
// frag linear index e = kt*4096 + nt*512 + lane*8 + j
// holds W[kt*32 + (lane>>4)*8 + j][nt*16 + (lane&15)] (0 beyond K)
__device__ __forceinline__ void pack_frag(int e, int K, const void* W, bool F, float scale,
                                          short* H, short* L){
    int j = e & 7, lane = (e >> 3) & 63, nt = (e >> 9) & 7, kt = e >> 12;
    int k = kt*32 + ((lane >> 4) & 3)*8 + j;
    int n = nt*16 + (lane & 15);
    float v = (k < K) ? ld(W, (size_t)k*128 + n, F) * scale : 0.f;
    unsigned short h = f2us(v);
    unsigned short l2 = f2us(v - us2f(h));
    H[e] = (short)h; L[e] = (short)l2;
}

// ---------------- prep1: fragment-packed raw weights + biases ----------------
__global__ __launch_bounds__(256) void prep1_kernel(
        const void* __restrict__ w20, const void* __restrict__ w21,
        const void* __restrict__ rw, const void* __restrict__ b20,
        const void* __restrict__ b21, const void* __restrict__ rb,
        short* __restrict__ w20rp_h, short* __restrict__ w20rp_l,
        short* __restrict__ w21p_h, short* __restrict__ w21p_l,
        short* __restrict__ rwp_h, short* __restrict__ rwp_l,
        float* __restrict__ b20r, float* __restrict__ bof, const int* __restrict__ flag){
    const bool F = (*flag != 0);
    int e = blockIdx.x*256 + threadIdx.x;
    if (e < 12288){ pack_frag(e, 70, w20, F, 1.f, w20rp_h, w20rp_l); return; }
    e -= 12288;
    if (e < 16384){ pack_frag(e, 128, w21, F, 1.f, w21p_h, w21p_l); return; }
    e -= 16384;
    if (e < 8192){ pack_frag(e, 64, rw, F, 1.f, rwp_h, rwp_l); return; }
    e -= 8192;
    if (e < 128){
        b20r[e] = ld(b20, e, F);
        bof[e]  = ld(b21, e, F) + ld(rb, e, F);
    }
}

// ---------------- BN2 stats: MFMA GEMM (X[64x96]@W20), sum/sumsq ----------------
__global__ __launch_bounds__(256) void bn2_stats(const float* __restrict__ agg,
        const short* __restrict__ w20rp_h, const short* __restrict__ w20rp_l,
        const float* __restrict__ b20r, double* __restrict__ sums){
    __shared__ short Xh[64*104];
    __shared__ short Xl[64*104];
    const int t = threadIdx.x, lane = t & 63, w = t >> 6;
    const int cn = lane & 15, kq = lane >> 4;
    for (int e = t; e < 64*34; e += 256){
        int r = e/34, k = 70 + (e - r*34);
        Xh[r*104+k] = 0; Xl[r*104+k] = 0;
    }
    float bias[8];
#pragma unroll
    for (int nt = 0; nt < 8; nt++) bias[nt] = b20r[nt*16 + cn];
    f32x4 accS[8], accQ[8];
#pragma unroll
    for (int nt = 0; nt < 8; nt++){
        f32x4 zz; zz[0]=0.f; zz[1]=0.f; zz[2]=0.f; zz[3]=0.f;
        accS[nt] = zz; accQ[nt] = zz;
    }
    for (int it = 0; it < 8; it++){
        const int rowbase = blockIdx.x*512 + it*64;
        __syncthreads();
        for (int e = t; e < 64*70; e += 256){
            int r = e/70, k = e - r*70;
            float v = agg[(size_t)rowbase*70 + e];
            unsigned short h = f2us(v);
            unsigned short l2 = f2us(v - us2f(h));
            Xh[r*104+k] = (short)h; Xl[r*104+k] = (short)l2;
        }
        __syncthreads();
        f32x4 z[8];
#pragma unroll
        for (int nt = 0; nt < 8; nt++){
            f32x4 a; a[0]=bias[nt]; a[1]=bias[nt]; a[2]=bias[nt]; a[3]=bias[nt];
            z[nt] = a;
        }
#pragma unroll
        for (int kt = 0; kt < 3; kt++){
            short8 Ah = *(const short8*)&Xh[(w*16 + cn)*104 + kt*32 + kq*8];
            short8 Al = *(const short8*)&Xl[(w*16 + cn)*104 + kt*32 + kq*8];
#pragma unroll
            for (int nt = 0; nt < 8; nt++){
                short8 Wh = ((const short8*)w20rp_h)[(kt*8+nt)*64 + lane];
                short8 Wl = ((const short8*)w20rp_l)[(kt*8+nt)*64 + lane];
                z[nt] = __builtin_amdgcn_mfma_f32_16x16x32_bf16(Ah, Wh, z[nt], 0, 0, 0);
                z[nt] = __builtin_amdgcn_mfma_f32_16x16x32_bf16(Al, Wh, z[nt], 0, 0, 0);
                z[nt] = __builtin_amdgcn_mfma_f32_16x16x32_bf16(Ah, Wl, z[nt], 0, 0, 0);
            }
        }
#pragma unroll
        for (int nt = 0; nt < 8; nt++){
#pragma unroll
            for (int rg = 0; rg < 4; rg++){
                accS[nt][rg] += z[nt][rg];
                accQ[nt][rg] = fmaf(z[nt][rg], z[nt][rg], accQ[nt][rg]);
            }
        }
    }
#pragma unroll
    for (int nt = 0; nt < 8; nt++){
        float s = (accS[nt][0] + accS[nt][1]) + (accS[nt][2] + accS[nt][3]);
        float q = (accQ[nt][0] + accQ[nt][1]) + (accQ[nt][2] + accQ[nt][3]);
        s += __shfl_xor(s, 16); s += __shfl_xor(s, 32);
        q += __shfl_xor(q, 16); q += __shfl_xor(q, 32);
        if (lane < 16){
            atomicAdd(&sums[nt*16 + cn], (double)s);
            atomicAdd(&sums[128 + nt*16 + cn], (double)q);
        }
    }
}

// ---------------- BN2 finalize ----------------
__global__ void bn2_final(const double* __restrict__ sums, const void* __restrict__ g2,
        const void* __restrict__ bt2, float* __restrict__ bn2, const int* __restrict__ flag){
    const bool F = (*flag != 0);
    int t = threadIdx.x; // 128
    const double K = 131072.0;
    double mean = sums[t] / K;
    double var = sums[128+t] / K - mean*mean;
    float sc = ld(g2, t, F) / sqrtf((float)var + 1e-5f);
    bn2[t] = sc;
    bn2[128+t] = ld(bt2, t, F) - (float)mean * sc;
}

// ---------------- prep2: bn2-folded w20 fragments + folded bias ----------------
__global__ __launch_bounds__(256) void prep2_kernel(
        const void* __restrict__ w20, const float* __restrict__ b20r,
        const float* __restrict__ bn2,
        short* __restrict__ w20p_h, short* __restrict__ w20p_l,
        float* __restrict__ b20f, const int* __restrict__ flag){
    const bool F = (*flag != 0);
    int e = blockIdx.x*256 + threadIdx.x;
    if (e < 12288){
        int j = e & 7, lane = (e >> 3) & 63, nt = (e >> 9) & 7, kt = e >> 12;
        int k = kt*32 + ((lane >> 4) & 3)*8 + j;
        int n = nt*16 + (lane & 15);
        float v = (k < 70) ? ld(w20, (size_t)k*128 + n, F) * bn2[n] : 0.f;
        unsigned short h = f2us(v);
        unsigned short l2 = f2us(v - us2f(h));
        w20p_h[e] = (short)h; w20p_l[e] = (short)l2;
        return;
    }
    e -= 12288;
    if (e < 128) b20f[e] = b20r[e]*bn2[e] + bn2[128+e];
}

// ---------------- final: full-MFMA (3-pass hi/lo), 64 rows/block ----------------
__global__ __launch_bounds__(256) void final_kernel(
        const float* __restrict__ agg, const void* __restrict__ f, const int* __restrict__ idx,
        const short* __restrict__ w20p_h, const short* __restrict__ w20p_l,
        const float* __restrict__ b20f,
        const short* __restrict__ w21p_h, const short* __restrict__ w21p_l,
        const short* __restrict__ rwp_h, const short* __restrict__ rwp_l,
        const float* __restrict__ bof,
        void* __restrict__ out, const int* __restrict__ flag){
    __shared__ short Xh[64*104];   // reused as Gh[64*88]
    __shared__ short Xl[64*104];   // reused as Gl[64*88]
    __shared__ short Yh[64*152];
    __shared__ short Yl[64*152];
    __shared__ float obuf[4][128];
    const bool F = (*flag != 0);
    const int t = threadIdx.x, lane = t & 63, w = t >> 6;
    const int cn = lane & 15, kq = lane >> 4;
    const int rowbase = blockIdx.x * 64;
    // zero X pad cols 70..103
    for (int e = t; e < 64*34; e += 256){
        int r = e/34, k = 70 + (e - r*34);
        Xh[r*104+k] = 0; Xl[r*104+k] = 0;
    }
    // stage X = agg rows (bf16 hi/lo)
    for (int e = t; e < 64*70; e += 256){
        int r = e/70, k = e - r*70;
        float v = agg[(size_t)rowbase*70 + e];
        unsigned short h = f2us(v);
        unsigned short l2 = f2us(v - us2f(h));
        Xh[r*104+k] = (short)h; Xl[r*104+k] = (short)l2;
    }
    __syncthreads();
    // GEMM1: z = X @ w20p + b20f  (bn2 pre-folded)
    f32x4 z[8];
#pragma unroll
    for (int nt = 0; nt < 8; nt++){
        float b = b20f[nt*16 + cn];
        f32x4 a; a[0]=b; a[1]=b; a[2]=b; a[3]=b;
        z[nt] = a;
    }
#pragma unroll
    for (int kt = 0; kt < 3; kt++){
        short8 Ah = *(const short8*)&Xh[(w*16 + cn)*104 + kt*32 + kq*8];
        short8 Al = *(const short8*)&Xl[(w*16 + cn)*104 + kt*32 + kq*8];
#pragma unroll
        for (int nt = 0; nt < 8; nt++){
            short8 Wh = ((const short8*)w20p_h)[(kt*8+nt)*64 + lane];
            short8 Wl = ((const short8*)w20p_l)[(kt*8+nt)*64 + lane];
            z[nt] = __builtin_amdgcn_mfma_f32_16x16x32_bf16(Ah, Wh, z[nt], 0, 0, 0);
            z[nt] = __builtin_amdgcn_mfma_f32_16x16x32_bf16(Al, Wh, z[nt], 0, 0, 0);
            z[nt] = __builtin_amdgcn_mfma_f32_16x16x32_bf16(Ah, Wl, z[nt], 0, 0, 0);
        }
    }
    __syncthreads();   // X dead now
    // Y = relu(z), store hi/lo in A-layout; C-layout: row = w*16 + kq*4 + reg, col = nt*16 + cn
#pragma unroll
    for (int nt = 0; nt < 8; nt++){
#pragma unroll
        for (int rg = 0; rg < 4; rg++){
            float y = fmaxf(z[nt][rg], 0.f);
            unsigned short h = f2us(y);
            unsigned short l2 = f2us(y - us2f(h));
            int row = w*16 + kq*4 + rg, col = nt*16 + cn;
            Yh[row*152+col] = (short)h; Yl[row*152+col] = (short)l2;
        }
    }
    // stage G = gathered f rows into X region (pitch 88)
    for (int e = t; e < 64*64; e += 256){
        int r = e >> 6, k = e & 63;
        int id = idx[rowbase + r];
        int b = (rowbase + r) >> 15;
        float v = (id >= 0) ? ld(f, (size_t)(b*NN+id)*64 + k, F) : 0.f;
        unsigned short h = f2us(v);
        unsigned short l2 = f2us(v - us2f(h));
        Xh[r*88+k] = (short)h; Xl[r*88+k] = (short)l2;
    }
    __syncthreads();
    // GEMM2 (Y @ w21p) + GEMM3 (G @ rwp), accumulate into acc2
    f32x4 acc2[8];
#pragma unroll
    for (int nt = 0; nt < 8; nt++){
        float b = bof[nt*16 + cn];
        f32x4 a; a[0]=b; a[1]=b; a[2]=b; a[3]=b;
        acc2[nt] = a;
    }
#pragma unroll
    for (int kt = 0; kt < 4; kt++){
        short8 Ah = *(const short8*)&Yh[(w*16 + cn)*152 + kt*32 + kq*8];
        short8 Al = *(const short8*)&Yl[(w*16 + cn)*152 + kt*32 + kq*8];
#pragma unroll
        for (int nt = 0; nt < 8; nt++){
            short8 Wh = ((const short8*)w21p_h)[(kt*8+nt)*64 + lane];
            short8 Wl = ((const short8*)w21p_l)[(kt*8+nt)*64 + lane];
            acc2[nt] = __builtin_amdgcn_mfma_f32_16x16x32_bf16(Ah, Wh, acc2[nt], 0, 0, 0);
            acc2[nt] = __builtin_amdgcn_mfma_f32_16x16x32_bf16(Al, Wh, acc2[nt], 0, 0, 0);
            acc2[nt] = __builtin_amdgcn_mfma_f32_16x16x32_bf16(Ah, Wl, acc2[nt], 0, 0, 0);
        }
    }
#pragma unroll
    for (int kt = 0; kt < 2; kt++){
        short8 Ah = *(const short8*)&Xh[(w*16 + cn)*88 + kt*32 + kq*8];
        short8 Al = *(const short8*)&Xl[(w*16 + cn)*88 + kt*32 + kq*8];
#pragma unroll
        for (int nt = 0; nt < 8; nt++){
            short8 Wh = ((const short8*)rwp_h)[(kt*8+nt)*64 + lane];
            short8 Wl = ((const short8*)rwp_l)[(kt*8+nt)*64 + lane];
            acc2[nt] = __builtin_amdgcn_mfma_f32_16x16x32_bf16(Ah, Wh, acc2[nt], 0, 0, 0);
            acc2[nt] = __builtin_amdgcn_mfma_f32_16x16x32_bf16(Al, Wh, acc2[nt], 0, 0, 0);
            acc2[nt] = __builtin_amdgcn_mfma_f32_16x16x32_bf16(Ah, Wl, acc2[nt], 0, 0, 0);
        }
    }
    // epilogue: gelu (exact erf) then max over the wave's 16 rows
#pragma unroll
    for (int nt = 0; nt < 8; nt++){
        float m = -3.4e38f;
#pragma unroll
        for (int rg = 0; rg < 4; rg++){
            float x = acc2[nt][rg];
            float y = 0.5f * x * (1.f + erff(x * 0.70710678118654752f));
            m = fmaxf(m, y);
        }
        m = fmaxf(m, __shfl_xor(m, 16));
        m = fmaxf(m, __shfl_xor(m, 32));
        if (lane < 16) obuf[w][nt*16 + cn] = m;
    }
    __syncthreads();
    {
        int g = t >> 7, c = t & 127;
        float y = fmaxf(obuf[2*g][c], obuf[2*g+1][c]);
        st(out, (size_t)blockIdx.x*256 + t, y, F);
    }
}

extern "C" void kernel_launch(void* const* d_in, const int* in_sizes, int n_in,
                              void* d_out, int out_size, void* d_ws, size_t ws_size,
                              hipStream_t stream){
    const void* xyz = d_in[0];
    const void* f   = d_in[1];
    const void* fpt = d_in[2];
    const void* w10 = d_in[3];
    const void* b10 = d_in[4];
    const void* g1  = d_in[5];
    const void* bt1 = d_in[6];
    const void* w11 = d_in[7];
    const void* b11 = d_in[8];
    const void* w20 = d_in[9];
    const void* b20 = d_in[10];
    const void* g2  = d_in[11];
    const void* bt2 = d_in[12];
    const void* w21 = d_in[13];
    const void* b21 = d_in[14];
    const void* rw  = d_in[15];
    const void* rb  = d_in[16];

    char* ws = (char*)d_ws;
    float*  nxf     = (float*) (ws + 0);         // 49152 B
    int*    idx     = (int*)   (ws + 65536);     // 524288 B
    double* M       = (double*)(ws + 655360);    // 105 f64
    float*  bn1     = (float*) (ws + 786432);    // 128 f32
    double* sums    = (double*)(ws + 917504);    // 256 f64
    float*  bn2     = (float*) (ws + 1048576);   // 256 f32
    int*    flag    = (int*)   (ws + 1050624);
    float*  b20r    = (float*) (ws + 1060864);   // 128 f32
    float*  bof     = (float*) (ws + 1061376);   // 128 f32
    float*  b20f    = (float*) (ws + 1061888);   // 128 f32
    short*  w20rp_h = (short*) (ws + 1064960);   // 12288 u16
    short*  w20rp_l = (short*) (ws + 1089536);
    short*  w20p_h  = (short*) (ws + 1114112);
    short*  w20p_l  = (short*) (ws + 1138688);
    short*  w21p_h  = (short*) (ws + 1163264);   // 16384 u16
    short*  w21p_l  = (short*) (ws + 1196032);
    short*  rwp_h   = (short*) (ws + 1228800);   // 8192 u16
    short*  rwp_l   = (short*) (ws + 1245184);
    float*  agg     = (float*) (ws + 2097152);   // 131072*70 f32

    init_kernel<<<1, 256, 0, stream>>>(xyz, M, sums, flag);
    fps_kernel<<<4, 256, 0, stream>>>(xyz, nxf, d_out, flag);
    ball_kernel<<<dim3(4, 32), 512, 0, stream>>>(xyz, nxf, idx, flag);
    prep1_kernel<<<145, 256, 0, stream>>>(w20, w21, rw, b20, b21, rb,
                                          w20rp_h, w20rp_l, w21p_h, w21p_l,
                                          rwp_h, rwp_l, b20r, bof, flag);
    bn1_stats<<<128, 256, 0, stream>>>(xyz, idx, fpt, M, flag);
    bn1_final<<<1, 128, 0, stream>>>(M, w10, b10, g1, bt1, bn1, flag);
    m1_kernel<<<1024, 256, 0, stream>>>(xyz, f, fpt, w10, b10, w11, b11, nxf, idx, bn1, agg, flag);
    bn2_stats<<<256, 256, 0, stream>>>(agg, w20rp_h, w20rp_l, b20r, sums);
    bn2_final<<<1, 128, 0, stream>>>(sums, g2, bt2, bn2, flag);
    prep2_kernel<<<49, 256, 0, stream>>>(w20, b20r, bn2, w20p_h, w20p_l, b20f, flag);
    final_kernel<<<2048, 256, 0, stream>>>(agg, f, idx, w20p_h, w20p_l, b20f,
                                           w21p_h, w21p_l, rwp_h, rwp_l, bof, d_out, flag);
}